// Round 7
// baseline (136.459 us; speedup 1.0000x reference)
//
#include <hip/hip_runtime.h>

// Focal Tversky loss over (8,10,512,512) fp32 logits, (8,512,512) int32 targets.
// argmax(softmax(x)) == argmax(x) -> no softmax needed. 84 MB read once.
//
// R2: ballot-based wave histogramming (no hot-path atomics) - kept.
// R4/R5: single-node fusion regressed (fence L2-flush storm; same-line atomic
//     funnel on the critical path). Two-node structure kept.
// R5-R6 key finding: VGPR_Count=28 - the allocator optimizes for occupancy and
//     rolls the channel loads through 2-3 regs -> ~3 outstanding loads/thread
//     -> latency-bound at ~2.5 TB/s. Totals R2/R3/R6 identical (131) because
//     source-level "batching" without a VGPR budget license changes nothing.
// R7: __launch_bounds__(256,2) (VGPR cap 256) + 2 pixel-groups per thread
//     (20 loads, ~90 VGPRs live, grid 1024): real 20-deep MLP per thread.

#define HW4     65536    // 512*512/4 (float4 groups per plane), = 2^16
#define NBLK    1024     // hist grid; NBLK*256 threads, 2 groups/thread
#define NTHREADS (NBLK * 256)   // 262144

// partial layout (transposed for coalesced reduce): pw[c*NBLK + block]
// c in [0,27): 0..8 TP, 9..17 target count, 18..26 pred count
__global__ __launch_bounds__(256, 2) void ftl_hist(const float* __restrict__ inp,
                                                   const int* __restrict__ tgt,
                                                   unsigned int* __restrict__ pw) {
    __shared__ unsigned int s[4][27];
    const int tid  = threadIdx.x;
    const int wave = tid >> 6;
    const int lane = tid & 63;

    const int i  = blockIdx.x * 256 + tid;     // group A index (in [0, 262144))
    const int b  = i >> 16;                    // image 0..3
    const int gi = i & (HW4 - 1);              // group within image
    // group B = i + 262144 -> same gi, image b+4

    const float4* f4 = reinterpret_cast<const float4*>(inp);
    const float4* baseA = f4 + (((size_t)(b * 10 + 1)) << 16) + gi;        // ch1, img b
    const float4* baseB = f4 + (((size_t)((b + 4) * 10 + 1)) << 16) + gi;  // ch1, img b+4

    // ---- issue ALL 20 loads first (licensed by launch_bounds VGPR cap) ----
    const float4 a0 = baseA[0];
    const float4 a1 = baseA[(size_t)1 << 16];
    const float4 a2 = baseA[(size_t)2 << 16];
    const float4 a3 = baseA[(size_t)3 << 16];
    const float4 a4 = baseA[(size_t)4 << 16];
    const float4 a5 = baseA[(size_t)5 << 16];
    const float4 a6 = baseA[(size_t)6 << 16];
    const float4 a7 = baseA[(size_t)7 << 16];
    const float4 a8 = baseA[(size_t)8 << 16];
    const float4 g0 = baseB[0];
    const float4 g1 = baseB[(size_t)1 << 16];
    const float4 g2 = baseB[(size_t)2 << 16];
    const float4 g3 = baseB[(size_t)3 << 16];
    const float4 g4 = baseB[(size_t)4 << 16];
    const float4 g5 = baseB[(size_t)5 << 16];
    const float4 g6 = baseB[(size_t)6 << 16];
    const float4 g7 = baseB[(size_t)7 << 16];
    const float4 g8 = baseB[(size_t)8 << 16];
    const int4   tA = reinterpret_cast<const int4*>(tgt)[i];
    const int4   tB = reinterpret_cast<const int4*>(tgt)[i + NTHREADS];

    // ---- argmax over channels 1..9, both groups ----
    float av0 = a0.x, av1 = a0.y, av2 = a0.z, av3 = a0.w;
    int   ac0 = 1,    ac1 = 1,    ac2 = 1,    ac3 = 1;
#define AM_A(W, C) \
    if (W.x > av0) { av0 = W.x; ac0 = C; } \
    if (W.y > av1) { av1 = W.y; ac1 = C; } \
    if (W.z > av2) { av2 = W.z; ac2 = C; } \
    if (W.w > av3) { av3 = W.w; ac3 = C; }
    AM_A(a1, 2) AM_A(a2, 3) AM_A(a3, 4) AM_A(a4, 5)
    AM_A(a5, 6) AM_A(a6, 7) AM_A(a7, 8) AM_A(a8, 9)
#undef AM_A
    float bv0 = g0.x, bv1 = g0.y, bv2 = g0.z, bv3 = g0.w;
    int   bc0 = 1,    bc1 = 1,    bc2 = 1,    bc3 = 1;
#define AM_B(W, C) \
    if (W.x > bv0) { bv0 = W.x; bc0 = C; } \
    if (W.y > bv1) { bv1 = W.y; bc1 = C; } \
    if (W.z > bv2) { bv2 = W.z; bc2 = C; } \
    if (W.w > bv3) { bv3 = W.w; bc3 = C; }
    AM_B(g1, 2) AM_B(g2, 3) AM_B(g3, 4) AM_B(g4, 5)
    AM_B(g5, 6) AM_B(g6, 7) AM_B(g7, 8) AM_B(g8, 9)
#undef AM_B

    unsigned int cTP[9], cT[9], cP[9];
#pragma unroll
    for (int j = 0; j < 9; ++j) { cTP[j] = 0u; cT[j] = 0u; cP[j] = 0u; }

    const unsigned long long vAx = __ballot(tA.x != 0);
    const unsigned long long vAy = __ballot(tA.y != 0);
    const unsigned long long vAz = __ballot(tA.z != 0);
    const unsigned long long vAw = __ballot(tA.w != 0);
    const unsigned long long vBx = __ballot(tB.x != 0);
    const unsigned long long vBy = __ballot(tB.y != 0);
    const unsigned long long vBz = __ballot(tB.z != 0);
    const unsigned long long vBw = __ballot(tB.w != 0);

#define COMP(TC, BC, VM) \
    {   const unsigned long long tm = __ballot(TC == c); \
        const unsigned long long pm = __ballot(BC == c); \
        cT[j]  += (unsigned int)__builtin_popcountll(tm); \
        cP[j]  += (unsigned int)__builtin_popcountll(pm & VM); \
        cTP[j] += (unsigned int)__builtin_popcountll(tm & pm); }
#pragma unroll
    for (int c = 1; c <= 9; ++c) {
        const int j = c - 1;
        COMP(tA.x, ac0, vAx) COMP(tA.y, ac1, vAy)
        COMP(tA.z, ac2, vAz) COMP(tA.w, ac3, vAw)
        COMP(tB.x, bc0, vBx) COMP(tB.y, bc1, vBy)
        COMP(tB.z, bc2, vBz) COMP(tB.w, bc3, vBw)
    }
#undef COMP

    if (lane == 0) {
#pragma unroll
        for (int j = 0; j < 9; ++j) {
            s[wave][j]      = cTP[j];
            s[wave][9 + j]  = cT[j];
            s[wave][18 + j] = cP[j];
        }
    }
    __syncthreads();
    if (tid < 27)
        pw[tid * NBLK + blockIdx.x] = s[0][tid] + s[1][tid] + s[2][tid] + s[3][tid];
}

// One block, 896 threads: 27 groups of 32 lanes each sum one counter row
// (coalesced), shuffle-reduce, thread 0 does the 9-term Tversky sum in double.
__global__ __launch_bounds__(896) void ftl_reduce(const unsigned int* __restrict__ pw,
                                                  float* __restrict__ out) {
    __shared__ double cs[27];
    const int tid = threadIdx.x;
    const int g = tid >> 5;
    const int l = tid & 31;
    if (g < 27) {
        unsigned int sum = 0;
        const unsigned int* row = pw + g * NBLK;
#pragma unroll 8
        for (int k = l; k < NBLK; k += 32) sum += row[k];
#pragma unroll
        for (int off = 16; off; off >>= 1) sum += __shfl_down(sum, off, 32);
        if (l == 0) cs[g] = (double)sum;
    }
    __syncthreads();
    if (tid == 0) {
        double loss = 0.0;
#pragma unroll
        for (int c = 0; c < 9; ++c) {
            const double TP = cs[c];
            const double FN = cs[9 + c]  - TP;
            const double FP = cs[18 + c] - TP;
            const double tv = (TP + 1.0) / (TP + 0.7 * FN + 0.3 * FP + 1.0);
            loss += pow(1.0 - tv, 4.0 / 3.0);
        }
        out[0] = (float)loss;
    }
}

extern "C" void kernel_launch(void* const* d_in, const int* in_sizes, int n_in,
                              void* d_out, int out_size, void* d_ws, size_t ws_size,
                              hipStream_t stream) {
    const float* inp = (const float*)d_in[0];
    const int*   tgt = (const int*)d_in[1];
    unsigned int* pw = (unsigned int*)d_ws;    // 27*NBLK partials, no init needed
    float* out = (float*)d_out;

    ftl_hist<<<dim3(NBLK), dim3(256), 0, stream>>>(inp, tgt, pw);
    ftl_reduce<<<dim3(1), dim3(896), 0, stream>>>(pw, out);
}